// Round 3
// baseline (1614.291 us; speedup 1.0000x reference)
//
#include <hip/hip_runtime.h>

// ---------------------------------------------------------------------------
// FCMNet: graph-conv autoencoder. Node tensors in (N, B*C) layout, B=16.
// Pools/unpools = bf16 MFMA GEMM (m97 structure, split-K via fp32 atomics).
// Convs: k_e = ec[e]·W materialized bf16 in kbuf, CSR-gather per dst with
// optional CO-split (blockIdx.y) for block-count-starved levels.
// ---------------------------------------------------------------------------

typedef __attribute__((ext_vector_type(8))) short bf16x8;
typedef __attribute__((ext_vector_type(4))) float f32x4;

__device__ inline unsigned bf1(float x){
  union {float f; unsigned u;} a; a.f = x;
  return (a.u + 0x7fffu + ((a.u >> 16) & 1u)) >> 16;   // RNE bf16
}
__device__ inline unsigned pack_bf2(float x, float y){ return bf1(x) | (bf1(y) << 16); }
__device__ inline float2 unp_bf2(unsigned u){
  union {unsigned i; float f;} a, b;
  a.i = u << 16; b.i = u & 0xffff0000u;
  return make_float2(a.f, b.f);
}

__device__ inline void gld_lds16(const void* g, void* l){
  __builtin_amdgcn_global_load_lds((const __attribute__((address_space(1))) void*)g,
                                   (__attribute__((address_space(3))) void*)l, 16, 0, 0);
}

// ---------------- utility ----------------
__global__ void k_zero_f32(float* __restrict__ p, int n){
  int i = blockIdx.x * 256 + threadIdx.x; if (i < n) p[i] = 0.f;
}
__global__ void k_zero_i32(int* __restrict__ p, int n){
  int i = blockIdx.x * 256 + threadIdx.x; if (i < n) p[i] = 0;
}
// x (16,12000,3) -> xT (12000,16,3)
__global__ void k_transpose_in(const float* __restrict__ x, float* __restrict__ xT){
  int gid = blockIdx.x * 256 + threadIdx.x;
  if (gid >= 16 * 12000 * 3) return;
  int b = gid / 36000; int r = gid % 36000; int n = r / 3; int c = r % 3;
  xT[n * 48 + b * 3 + c] = x[gid];
}

// ---------------- CSR build ----------------
__global__ void k_count(const int* __restrict__ ei, int E, int* __restrict__ cnt){
  int e = blockIdx.x * 256 + threadIdx.x;
  if (e < E) atomicAdd(&cnt[ei[E + e]], 1);
}
__global__ void k_scan(int* __restrict__ cnt, int* __restrict__ rowptr, int n){
  __shared__ int s[256];
  __shared__ int carryS;
  int t = threadIdx.x;
  if (t == 0){ carryS = 0; rowptr[0] = 0; }
  __syncthreads();
  for (int base = 0; base < n; base += 256){
    int i = base + t;
    int v = (i < n) ? cnt[i] : 0;
    s[t] = v;
    __syncthreads();
    for (int off = 1; off < 256; off <<= 1){
      int a = (t >= off) ? s[t - off] : 0;
      __syncthreads();
      s[t] += a;
      __syncthreads();
    }
    int carry = carryS;
    int incl = s[t];
    if (i < n){ rowptr[i + 1] = carry + incl; cnt[i] = carry + incl - v; }
    __syncthreads();
    if (t == 255) carryS = carry + s[255];
    __syncthreads();
  }
}
__global__ void k_fill(const int* __restrict__ ei, int E, int* __restrict__ cursor, int* __restrict__ perm){
  int e = blockIdx.x * 256 + threadIdx.x;
  if (e < E){ int p = atomicAdd(&cursor[ei[E + e]], 1); perm[p] = e; }
}

// ---------------- fp32 -> bf16 converters for GEMM operands ----------------
__global__ void k_cvt_pad(const float* __restrict__ in, unsigned short* __restrict__ out,
                          int M, int K, int Kp, int total8){
  int gid = blockIdx.x * 256 + threadIdx.x;
  if (gid >= total8) return;
  int j = gid * 8;
  int row = j / Kp, col = j % Kp;
  float v[8];
  if (row < M && col + 8 <= K && (K & 3) == 0){
    const float* p = in + (size_t)row * K + col;
    float4 x0 = *(const float4*)p;
    float4 x1 = *(const float4*)(p + 4);
    v[0]=x0.x; v[1]=x0.y; v[2]=x0.z; v[3]=x0.w;
    v[4]=x1.x; v[5]=x1.y; v[6]=x1.z; v[7]=x1.w;
  } else {
    #pragma unroll
    for (int c = 0; c < 8; ++c)
      v[c] = (row < M && col + c < K) ? in[(size_t)row * K + col + c] : 0.f;
  }
  uint4 o;
  o.x = pack_bf2(v[0], v[1]); o.y = pack_bf2(v[2], v[3]);
  o.z = pack_bf2(v[4], v[5]); o.w = pack_bf2(v[6], v[7]);
  *(uint4*)(out + (size_t)gid * 8) = o;
}
__global__ void k_cvt_T(const float* __restrict__ in, unsigned short* __restrict__ out,
                        int K, int N, int Kp){
  __shared__ float ts[32][33];
  int t = threadIdx.x;
  int k0 = blockIdx.x * 32, n0 = blockIdx.y * 32;
  #pragma unroll
  for (int rep = 0; rep < 4; ++rep){
    int i = t + rep * 256;
    int kr = i >> 5, nc = i & 31;
    ts[kr][nc] = (k0 + kr < K) ? in[(size_t)(k0 + kr) * N + n0 + nc] : 0.f;
  }
  __syncthreads();
  #pragma unroll
  for (int rep = 0; rep < 4; ++rep){
    int i = t + rep * 256;
    int nr = i >> 5, kc = i & 31;
    out[(size_t)(n0 + nr) * Kp + k0 + kc] = (unsigned short)bf1(ts[kc][nr]);
  }
}

// ---------------- bf16 MFMA GEMM: C(M,N) (+)= A(Mp,Kp) @ Bt(N,Kp)^T ----------
__global__ __launch_bounds__(256) void k_mgemm(const unsigned short* __restrict__ A,
                                               const unsigned short* __restrict__ Bt,
                                               float* __restrict__ C,
                                               int M, int N, int Kp, int Kc, int splitK){
  __shared__ __align__(16) short As[4096];   // 128 rows x 32 k bf16, chunk-major
  __shared__ __align__(16) short Bs[4096];
  int t = threadIdx.x, lane = t & 63, w = t >> 6;
  int n0 = blockIdx.x << 7, m0 = blockIdx.y << 7;
  int k0 = blockIdx.z * Kc;
  int kend = min(Kp, k0 + Kc);
  int s0 = w * 128 + lane, s1 = s0 + 64;
  const unsigned short* gA0 = A + (size_t)(m0 + (s0 & 127)) * Kp + (s0 >> 7) * 8 + k0;
  const unsigned short* gA1 = A + (size_t)(m0 + (s1 & 127)) * Kp + (s1 >> 7) * 8 + k0;
  const unsigned short* gB0 = Bt + (size_t)(n0 + (s0 & 127)) * Kp + (s0 >> 7) * 8 + k0;
  const unsigned short* gB1 = Bt + (size_t)(n0 + (s1 & 127)) * Kp + (s1 >> 7) * 8 + k0;
  short* lA0 = As + (size_t)(w * 128) * 8;
  short* lA1 = As + (size_t)(w * 128 + 64) * 8;
  short* lB0 = Bs + (size_t)(w * 128) * 8;
  short* lB1 = Bs + (size_t)(w * 128 + 64) * 8;
  f32x4 acc[4][4];
  #pragma unroll
  for (int mt = 0; mt < 4; ++mt)
    #pragma unroll
    for (int nt = 0; nt < 4; ++nt){ acc[mt][nt][0]=0.f; acc[mt][nt][1]=0.f; acc[mt][nt][2]=0.f; acc[mt][nt][3]=0.f; }
  int q = lane >> 4, r = lane & 15;
  int mrow = (w >> 1) * 64, nrow = (w & 1) * 64;
  const short* pa = As + (size_t)(q * 128 + mrow + r) * 8;
  const short* pb = Bs + (size_t)(q * 128 + nrow + r) * 8;
  for (int kk = k0; kk < kend; kk += 32){
    gld_lds16(gA0, lA0); gld_lds16(gA1, lA1);
    gld_lds16(gB0, lB0); gld_lds16(gB1, lB1);
    gA0 += 32; gA1 += 32; gB0 += 32; gB1 += 32;
    __syncthreads();
    bf16x8 af[4], bg[4];
    #pragma unroll
    for (int mt = 0; mt < 4; ++mt) af[mt] = *(const bf16x8*)(pa + mt * 128);
    #pragma unroll
    for (int nt = 0; nt < 4; ++nt) bg[nt] = *(const bf16x8*)(pb + nt * 128);
    #pragma unroll
    for (int mt = 0; mt < 4; ++mt)
      #pragma unroll
      for (int nt = 0; nt < 4; ++nt)
        acc[mt][nt] = __builtin_amdgcn_mfma_f32_16x16x32_bf16(af[mt], bg[nt], acc[mt][nt], 0, 0, 0);
    __syncthreads();
  }
  int mb = m0 + mrow + q * 4;
  int nb = n0 + nrow + r;
  #pragma unroll
  for (int mt = 0; mt < 4; ++mt){
    #pragma unroll
    for (int reg = 0; reg < 4; ++reg){
      int m = mb + mt * 16 + reg;
      if (m < M){
        float* cp = C + (size_t)m * N + nb;
        if (splitK > 1){
          #pragma unroll
          for (int nt = 0; nt < 4; ++nt) atomicAdd(cp + nt * 16, acc[mt][nt][reg]);
        } else {
          #pragma unroll
          for (int nt = 0; nt < 4; ++nt) cp[nt * 16] = acc[mt][nt][reg];
        }
      }
    }
  }
}

// ---------------- k materialization ----------------
__global__ __launch_bounds__(256) void k_kmat_big(const float* __restrict__ ec, const float* __restrict__ W,
                                                  unsigned short* __restrict__ kbuf, int E, int CiCo4){
  __shared__ float ecs[128];
  int t = threadIdx.x;
  int e0 = blockIdx.y * 8;
  if (t < 128){ int el = t >> 4, w = t & 15; int e = e0 + el; ecs[t] = (e < E) ? ec[e * 16 + w] : 0.f; }
  __syncthreads();
  int j4 = blockIdx.x * 256 + t;
  const float4* W4 = (const float4*)W;
  float4 w16[16];
  #pragma unroll
  for (int w = 0; w < 16; ++w) w16[w] = W4[(size_t)w * CiCo4 + j4];
  uint2* k2 = (uint2*)kbuf;
  #pragma unroll 1
  for (int el = 0; el < 8; ++el){
    int e = e0 + el; if (e >= E) break;
    float4 a = {0.f, 0.f, 0.f, 0.f};
    #pragma unroll
    for (int w = 0; w < 16; ++w){
      float s = ecs[el * 16 + w];
      a.x += s * w16[w].x; a.y += s * w16[w].y; a.z += s * w16[w].z; a.w += s * w16[w].w;
    }
    k2[(size_t)e * CiCo4 + j4] = make_uint2(pack_bf2(a.x, a.y), pack_bf2(a.z, a.w));
  }
}
__global__ __launch_bounds__(256) void k_kmat_small(const float* __restrict__ ec, const float* __restrict__ W,
                                                    unsigned short* __restrict__ kbuf, int E){
  __shared__ float4 Ws[16 * 24];
  __shared__ float ecs[32 * 16];
  int t = threadIdx.x;
  for (int i = t; i < 384; i += 256) Ws[i] = ((const float4*)W)[i];
  int e0 = blockIdx.x * 32;
  for (int i = t; i < 512; i += 256){ int el = i >> 4, w = i & 15; int e = e0 + el; ecs[i] = (e < E) ? ec[e * 16 + w] : 0.f; }
  __syncthreads();
  int el = t >> 3, jj = t & 7;
  int e = e0 + el;
  if (e >= E) return;
  uint2* k2 = (uint2*)kbuf;
  #pragma unroll 1
  for (int rep = 0; rep < 3; ++rep){
    int j4 = jj + rep * 8;
    float4 a = {0.f, 0.f, 0.f, 0.f};
    #pragma unroll
    for (int w = 0; w < 16; ++w){
      float s = ecs[el * 16 + w];
      float4 wv = Ws[w * 24 + j4];
      a.x += s * wv.x; a.y += s * wv.y; a.z += s * wv.z; a.w += s * wv.w;
    }
    k2[(size_t)e * 24 + j4] = make_uint2(pack_bf2(a.x, a.y), pack_bf2(a.z, a.w));
  }
}

// ---------------- level-0 convs ----------------
__global__ __launch_bounds__(256) void k_conv_l0_enc(const float* __restrict__ xT, const unsigned short* __restrict__ kbuf,
                                                     const int* __restrict__ ei, const int* __restrict__ rowptr,
                                                     const int* __restrict__ perm, const float* __restrict__ bias,
                                                     float* __restrict__ out){
  int gid = blockIdx.x * 256 + threadIdx.x;
  int n = gid >> 4, b = gid & 15;
  if (n >= 12000) return;
  float acc[32];
  #pragma unroll
  for (int o = 0; o < 32; ++o) acc[o] = 0.f;
  int r1 = rowptr[n + 1];
  for (int r = rowptr[n]; r < r1; ++r){
    int e = perm[r];
    int src = ei[e];
    const float* xp = xT + src * 48 + b * 3;
    float xv[3] = {xp[0], xp[1], xp[2]};
    const uint4* kq = (const uint4*)(kbuf + (size_t)e * 96);
    #pragma unroll
    for (int i = 0; i < 3; ++i){
      #pragma unroll
      for (int o8 = 0; o8 < 4; ++o8){
        uint4 u = kq[i * 4 + o8];
        float2 f0 = unp_bf2(u.x), f1 = unp_bf2(u.y), f2 = unp_bf2(u.z), f3 = unp_bf2(u.w);
        int ob = o8 * 8;
        acc[ob + 0] += xv[i] * f0.x; acc[ob + 1] += xv[i] * f0.y;
        acc[ob + 2] += xv[i] * f1.x; acc[ob + 3] += xv[i] * f1.y;
        acc[ob + 4] += xv[i] * f2.x; acc[ob + 5] += xv[i] * f2.y;
        acc[ob + 6] += xv[i] * f3.x; acc[ob + 7] += xv[i] * f3.y;
      }
    }
  }
  float4* op = (float4*)(out + (size_t)n * 512 + b * 32);
  #pragma unroll
  for (int o4 = 0; o4 < 8; ++o4){
    float4 v;
    v.x = fmaxf(acc[o4 * 4 + 0] + bias[o4 * 4 + 0], 0.f);
    v.y = fmaxf(acc[o4 * 4 + 1] + bias[o4 * 4 + 1], 0.f);
    v.z = fmaxf(acc[o4 * 4 + 2] + bias[o4 * 4 + 2], 0.f);
    v.w = fmaxf(acc[o4 * 4 + 3] + bias[o4 * 4 + 3], 0.f);
    op[o4] = v;
  }
}
__global__ __launch_bounds__(256) void k_conv_l0_dec(const float* __restrict__ xin, const unsigned short* __restrict__ kbuf,
                                                     const int* __restrict__ ei, const int* __restrict__ rowptr,
                                                     const int* __restrict__ perm, const float* __restrict__ bias,
                                                     float* __restrict__ out){
  int gid = blockIdx.x * 256 + threadIdx.x;
  int n = gid >> 4, b = gid & 15;
  if (n >= 12000) return;
  float acc0 = 0.f, acc1 = 0.f, acc2 = 0.f;
  int r1 = rowptr[n + 1];
  for (int r = rowptr[n]; r < r1; ++r){
    int e = perm[r];
    int src = ei[e];
    const float4* xr = (const float4*)(xin + (size_t)src * 512 + b * 32);
    const unsigned* kw = (const unsigned*)(kbuf + (size_t)e * 96);
    #pragma unroll
    for (int c = 0; c < 8; ++c){
      float4 xv = xr[c];
      float2 p0 = unp_bf2(kw[6 * c + 0]);
      float2 p1 = unp_bf2(kw[6 * c + 1]);
      float2 p2 = unp_bf2(kw[6 * c + 2]);
      float2 p3 = unp_bf2(kw[6 * c + 3]);
      float2 p4 = unp_bf2(kw[6 * c + 4]);
      float2 p5 = unp_bf2(kw[6 * c + 5]);
      acc0 += xv.x * p0.x; acc1 += xv.x * p0.y; acc2 += xv.x * p1.x;
      acc0 += xv.y * p1.y; acc1 += xv.y * p2.x; acc2 += xv.y * p2.y;
      acc0 += xv.z * p3.x; acc1 += xv.z * p3.y; acc2 += xv.z * p4.x;
      acc0 += xv.w * p4.y; acc1 += xv.w * p5.x; acc2 += xv.w * p5.y;
    }
  }
  float* op = out + (size_t)b * 36000 + n * 3;
  op[0] = acc0 + bias[0];
  op[1] = acc1 + bias[1];
  op[2] = acc2 + bias[2];
}

// ---------------- mid-level conv, CO-split S via blockIdx.y ----------------
template<int CI, int CO, int S, bool RELU>
__global__ __launch_bounds__(256) void k_conv_mid(const float* __restrict__ xin, const unsigned short* __restrict__ kbuf,
                                                  const int* __restrict__ ei, const int* __restrict__ rowptr,
                                                  const int* __restrict__ perm, const float* __restrict__ bias,
                                                  float* __restrict__ out){
  constexpr int COC = CO / S;           // this block's output-channel chunk
  constexpr int V   = COC / 16;
  constexpr int IT  = (CI > 64) ? 64 : CI;
  constexpr int NIH = CI / IT;
  constexpr int COP = COC + 4;
  constexpr int XP  = IT + 4;
  __shared__ float ks[IT * COP];
  __shared__ float xs[16 * XP];
  int n = blockIdx.x, cy = blockIdx.y;
  int ob0 = cy * COC;
  int t = threadIdx.x;
  int og = t >> 4, b = t & 15;
  float acc[V];
  #pragma unroll
  for (int j = 0; j < V; ++j) acc[j] = 0.f;
  int r0 = rowptr[n], r1 = rowptr[n + 1];
  for (int r = r0; r < r1; ++r){
    int e = perm[r];
    int src = ei[e];
    const float4* xbase = (const float4*)(xin + (size_t)src * (16 * CI));
    for (int ih = 0; ih < NIH; ++ih){
      __syncthreads();
      const uint4* kb = (const uint4*)(kbuf + (size_t)e * (CI * CO) + ih * (IT * CO));
      constexpr int KS8 = IT * COC / 8;
      for (int i8 = t; i8 < KS8; i8 += 256){
        int i = (i8 * 8) / COC, o = (i8 * 8) % COC;
        uint4 u = kb[(i * CO + ob0 + o) >> 3];
        float* d = &ks[i * COP + o];
        float2 f0 = unp_bf2(u.x), f1 = unp_bf2(u.y), f2 = unp_bf2(u.z), f3 = unp_bf2(u.w);
        *(float4*)&d[0] = make_float4(f0.x, f0.y, f1.x, f1.y);
        *(float4*)&d[4] = make_float4(f2.x, f2.y, f3.x, f3.y);
      }
      constexpr int XS4 = 16 * IT / 4;
      for (int i4 = t; i4 < XS4; i4 += 256){
        int bb = i4 / (IT / 4), iq = i4 % (IT / 4);
        float4 v = xbase[bb * (CI / 4) + ih * (IT / 4) + iq];
        *(float4*)&xs[bb * XP + iq * 4] = v;
      }
      __syncthreads();
      #pragma unroll 4
      for (int i = 0; i < IT; ++i){
        float xv = xs[b * XP + i];
        if constexpr (V == 8){
          const float4* kp = (const float4*)&ks[i * COP + og * 8];
          float4 p0 = kp[0], p1 = kp[1];
          acc[0] += xv * p0.x; acc[1] += xv * p0.y; acc[2] += xv * p0.z; acc[3] += xv * p0.w;
          acc[4] += xv * p1.x; acc[5] += xv * p1.y; acc[6] += xv * p1.z; acc[7] += xv * p1.w;
        } else if constexpr (V == 4){
          float4 p0 = *(const float4*)&ks[i * COP + og * 4];
          acc[0] += xv * p0.x; acc[1] += xv * p0.y; acc[2] += xv * p0.z; acc[3] += xv * p0.w;
        } else {
          float2 p0 = *(const float2*)&ks[i * COP + og * 2];
          acc[0] += xv * p0.x; acc[1] += xv * p0.y;
        }
      }
    }
  }
  float* op = out + (size_t)n * (16 * CO) + b * CO + ob0 + og * V;
  #pragma unroll
  for (int j = 0; j < V; ++j){
    float v = acc[j] + bias[ob0 + og * V + j];
    if (RELU) v = fmaxf(v, 0.f);
    op[j] = v;
  }
}

// ---------------- bottleneck FCs ----------------
__global__ void k_encfc(const float* __restrict__ x, const float* __restrict__ encW,
                        const float* __restrict__ encb, float* __restrict__ z){
  __shared__ float red[128];
  int bq = blockIdx.x; int b = bq >> 3, q = bq & 7;
  int t = threadIdx.x;
  float s = 0.f;
  for (int j = t; j < 6016; j += 128){
    int n = j >> 7, c = j & 127;
    s += x[n * 2048 + b * 128 + c] * encW[q * 6016 + j];
  }
  red[t] = s; __syncthreads();
  for (int o = 64; o > 0; o >>= 1){ if (t < o) red[t] += red[t + o]; __syncthreads(); }
  if (t == 0) z[b * 8 + q] = red[0] + encb[q];
}
__global__ void k_decfc(const float* __restrict__ z, const float* __restrict__ decW,
                        const float* __restrict__ decb, float* __restrict__ y){
  int gid = blockIdx.x * 256 + threadIdx.x;
  if (gid >= 6016 * 16) return;
  int c = gid & 127, bn = gid >> 7; int b = bn & 15, n = bn >> 4;
  int j = n * 128 + c;
  float s = decb[j];
  #pragma unroll
  for (int q = 0; q < 8; ++q) s += z[b * 8 + q] * decW[j * 8 + q];
  y[gid] = s;
}

// ---------------------------------------------------------------------------
extern "C" void kernel_launch(void* const* d_in, const int* in_sizes, int n_in,
                              void* d_out, int out_size, void* d_ws, size_t ws_size,
                              hipStream_t stream){
  const float* x   = (const float*)d_in[0];
  const int*   ei0 = (const int*)d_in[1];  const float* ec0 = (const float*)d_in[2];
  const int*   ei1 = (const int*)d_in[3];  const float* ec1 = (const float*)d_in[4];
  const int*   ei2 = (const int*)d_in[5];  const float* ec2 = (const float*)d_in[6];
  const int*   ei3 = (const int*)d_in[7];  const float* ec3 = (const float*)d_in[8];
  const float* Wc0 = (const float*)d_in[11], *bc0 = (const float*)d_in[12];
  const float* Wd0 = (const float*)d_in[13], *bd0 = (const float*)d_in[14];
  const float* dm0 = (const float*)d_in[15], *um0 = (const float*)d_in[16];
  const float* Wc1 = (const float*)d_in[17], *bc1 = (const float*)d_in[18];
  const float* Wd1 = (const float*)d_in[19], *bd1 = (const float*)d_in[20];
  const float* dm1 = (const float*)d_in[21], *um1 = (const float*)d_in[22];
  const float* Wc2 = (const float*)d_in[23], *bc2 = (const float*)d_in[24];
  const float* Wd2 = (const float*)d_in[25], *bd2 = (const float*)d_in[26];
  const float* dm2 = (const float*)d_in[27], *um2 = (const float*)d_in[28];
  const float* Wc3 = (const float*)d_in[29], *bc3 = (const float*)d_in[30];
  const float* Wd3 = (const float*)d_in[31], *bd3 = (const float*)d_in[32];
  const float* dm3 = (const float*)d_in[33], *um3 = (const float*)d_in[34];
  const float* encW = (const float*)d_in[35], *encb = (const float*)d_in[36];
  const float* decW = (const float*)d_in[37], *decb = (const float*)d_in[38];

  // workspace layout (~138 MiB)
  char* wsb = (char*)d_ws;
  unsigned short* kbuf = (unsigned short*)wsb;                    // shared with Abf
  unsigned short* Abf  = kbuf;
  float* bufA = (float*)(wsb + 73728000);
  float* bufB = (float*)(wsb + 98304000);
  unsigned short* Bt = (unsigned short*)(wsb + 122880000);
  float* xT   = (float*)(wsb + 135168000);
  float* zb   = (float*)(wsb + 137472000);
  int* ip = (int*)(wsb + 137472512);
  int* cnt0 = ip; ip += 12000;
  int* cnt1 = ip; ip += 3000;
  int* cnt2 = ip; ip += 750;
  int* cnt3 = ip; ip += 188;
  int* row0 = ip; ip += 12001;
  int* row1 = ip; ip += 3001;
  int* row2 = ip; ip += 751;
  int* row3 = ip; ip += 189;
  int* perm0 = ip; ip += 72000;
  int* perm1 = ip; ip += 18000;
  int* perm2 = ip; ip += 4500;
  int* perm3 = ip; ip += 1128;

  dim3 blk(256);
  // input transpose + CSR build
  k_transpose_in<<<2250, blk, 0, stream>>>(x, xT);
  k_zero_i32<<<63, blk, 0, stream>>>(cnt0, 15938);
  k_count<<<282, blk, 0, stream>>>(ei0, 72000, cnt0);
  k_count<<<71,  blk, 0, stream>>>(ei1, 18000, cnt1);
  k_count<<<18,  blk, 0, stream>>>(ei2, 4500, cnt2);
  k_count<<<5,   blk, 0, stream>>>(ei3, 1128, cnt3);
  k_scan<<<1, blk, 0, stream>>>(cnt0, row0, 12000);
  k_scan<<<1, blk, 0, stream>>>(cnt1, row1, 3000);
  k_scan<<<1, blk, 0, stream>>>(cnt2, row2, 750);
  k_scan<<<1, blk, 0, stream>>>(cnt3, row3, 188);
  k_fill<<<282, blk, 0, stream>>>(ei0, 72000, cnt0, perm0);
  k_fill<<<71,  blk, 0, stream>>>(ei1, 18000, cnt1, perm1);
  k_fill<<<18,  blk, 0, stream>>>(ei2, 4500, cnt2, perm2);
  k_fill<<<5,   blk, 0, stream>>>(ei3, 1128, cnt3, perm3);

  // ---- encoder ----
  k_kmat_small<<<2250, blk, 0, stream>>>(ec0, Wc0, kbuf, 72000);
  k_conv_l0_enc<<<750, blk, 0, stream>>>(xT, kbuf, ei0, row0, perm0, bc0, bufA);          // a0 (12000,512)
  k_cvt_T<<<dim3(375, 16), blk, 0, stream>>>(bufA, Bt, 12000, 512, 12000);
  k_cvt_pad<<<18000, blk, 0, stream>>>(dm0, Abf, 3000, 12000, 12000, 4608000);
  k_zero_f32<<<6000, blk, 0, stream>>>(bufB, 1536000);
  k_mgemm<<<dim3(4, 24, 12), blk, 0, stream>>>(Abf, Bt, bufB, 3000, 512, 12000, 1024, 12); // p0 (3000,512)
  k_kmat_big<<<dim3(2, 2250), blk, 0, stream>>>(ec1, Wc1, kbuf, 18000, 512);
  k_conv_mid<32, 64, 1, true><<<dim3(3000, 1), blk, 0, stream>>>(bufB, kbuf, ei1, row1, perm1, bc1, bufA); // a1
  k_cvt_T<<<dim3(94, 32), blk, 0, stream>>>(bufA, Bt, 3000, 1024, 3008);
  k_cvt_pad<<<1128, blk, 0, stream>>>(dm1, Abf, 750, 3000, 3008, 288768);
  k_zero_f32<<<3000, blk, 0, stream>>>(bufB, 768000);
  k_mgemm<<<dim3(8, 6, 16), blk, 0, stream>>>(Abf, Bt, bufB, 750, 1024, 3008, 192, 16);   // p1 (750,1024)
  k_kmat_big<<<dim3(8, 563), blk, 0, stream>>>(ec2, Wc2, kbuf, 4500, 2048);
  k_conv_mid<64, 128, 4, true><<<dim3(750, 4), blk, 0, stream>>>(bufB, kbuf, ei2, row2, perm2, bc2, bufA); // a2
  k_cvt_T<<<dim3(24, 64), blk, 0, stream>>>(bufA, Bt, 750, 2048, 768);
  k_cvt_pad<<<96, blk, 0, stream>>>(dm2, Abf, 188, 750, 768, 24576);
  k_zero_f32<<<1504, blk, 0, stream>>>(bufB, 385024);
  k_mgemm<<<dim3(16, 2, 12), blk, 0, stream>>>(Abf, Bt, bufB, 188, 2048, 768, 64, 12);    // p2 (188,2048)
  k_kmat_big<<<dim3(16, 141), blk, 0, stream>>>(ec3, Wc3, kbuf, 1128, 4096);
  k_conv_mid<128, 128, 4, true><<<dim3(188, 4), blk, 0, stream>>>(bufB, kbuf, ei3, row3, perm3, bc3, bufA); // a3
  k_cvt_T<<<dim3(6, 64), blk, 0, stream>>>(bufA, Bt, 188, 2048, 192);
  k_cvt_pad<<<12, blk, 0, stream>>>(dm3, Abf, 47, 188, 192, 3072);
  k_zero_f32<<<376, blk, 0, stream>>>(bufB, 96256);
  k_mgemm<<<dim3(16, 1, 6), blk, 0, stream>>>(Abf, Bt, bufB, 47, 2048, 192, 32, 6);       // p3 (47,2048)

  // ---- bottleneck ----
  k_encfc<<<128, dim3(128), 0, stream>>>(bufB, encW, encb, zb);
  k_decfc<<<376, blk, 0, stream>>>(zb, decW, decb, bufA);                                 // y' (47,2048)

  // ---- decoder ----
  k_cvt_T<<<dim3(2, 64), blk, 0, stream>>>(bufA, Bt, 47, 2048, 64);
  k_cvt_pad<<<8, blk, 0, stream>>>(um3, Abf, 188, 47, 64, 2048);
  k_zero_f32<<<1504, blk, 0, stream>>>(bufB, 385024);
  k_mgemm<<<dim3(16, 2, 2), blk, 0, stream>>>(Abf, Bt, bufB, 188, 2048, 64, 32, 2);       // u3 (188,2048)
  k_kmat_big<<<dim3(16, 141), blk, 0, stream>>>(ec3, Wd0, kbuf, 1128, 4096);
  k_conv_mid<128, 128, 4, true><<<dim3(188, 4), blk, 0, stream>>>(bufB, kbuf, ei3, row3, perm3, bd0, bufA); // d0
  k_cvt_T<<<dim3(6, 64), blk, 0, stream>>>(bufA, Bt, 188, 2048, 192);
  k_cvt_pad<<<72, blk, 0, stream>>>(um2, Abf, 750, 188, 192, 18432);
  k_zero_f32<<<6000, blk, 0, stream>>>(bufB, 1536000);
  k_mgemm<<<dim3(16, 6, 6), blk, 0, stream>>>(Abf, Bt, bufB, 750, 2048, 192, 32, 6);      // u2 (750,2048)
  k_kmat_big<<<dim3(8, 563), blk, 0, stream>>>(ec2, Wd1, kbuf, 4500, 2048);
  k_conv_mid<128, 64, 2, true><<<dim3(750, 2), blk, 0, stream>>>(bufB, kbuf, ei2, row2, perm2, bd1, bufA); // d1
  k_cvt_T<<<dim3(24, 32), blk, 0, stream>>>(bufA, Bt, 750, 1024, 768);
  k_cvt_pad<<<1152, blk, 0, stream>>>(um1, Abf, 3000, 750, 768, 294912);
  k_zero_f32<<<12000, blk, 0, stream>>>(bufB, 3072000);
  k_mgemm<<<dim3(8, 24, 4), blk, 0, stream>>>(Abf, Bt, bufB, 3000, 1024, 768, 192, 4);    // u1 (3000,1024)
  k_kmat_big<<<dim3(2, 2250), blk, 0, stream>>>(ec1, Wd2, kbuf, 18000, 512);
  k_conv_mid<64, 32, 1, true><<<dim3(3000, 1), blk, 0, stream>>>(bufB, kbuf, ei1, row1, perm1, bd2, bufA); // d2
  k_cvt_T<<<dim3(94, 16), blk, 0, stream>>>(bufA, Bt, 3000, 512, 3008);
  k_cvt_pad<<<17672, blk, 0, stream>>>(um0, Abf, 12000, 3000, 3008, 4524032);
  k_zero_f32<<<24000, blk, 0, stream>>>(bufB, 6144000);
  k_mgemm<<<dim3(4, 94, 4), blk, 0, stream>>>(Abf, Bt, bufB, 12000, 512, 3008, 768, 4);   // u0 (12000,512)
  k_kmat_small<<<2250, blk, 0, stream>>>(ec0, Wd3, kbuf, 72000);
  k_conv_l0_dec<<<750, blk, 0, stream>>>(bufB, kbuf, ei0, row0, perm0, bd3, (float*)d_out);
}

// Round 4
// 1445.866 us; speedup vs baseline: 1.1165x; 1.1165x over previous
//
#include <hip/hip_runtime.h>

// ---------------------------------------------------------------------------
// FCMNet: graph-conv autoencoder. Node tensors in (N, B*C) layout, B=16.
// Pools/unpools = bf16 MFMA GEMM (double-buffered LDS, split-K via atomics).
// Convs: k_e = ec[e]·W materialized bf16 in kbuf, CSR-gather per dst with
// CO-split (blockIdx.y) for block-count-starved levels.
// ---------------------------------------------------------------------------

typedef __attribute__((ext_vector_type(8))) short bf16x8;
typedef __attribute__((ext_vector_type(4))) float f32x4;

__device__ inline unsigned bf1(float x){
  union {float f; unsigned u;} a; a.f = x;
  return (a.u + 0x7fffu + ((a.u >> 16) & 1u)) >> 16;   // RNE bf16
}
__device__ inline unsigned pack_bf2(float x, float y){ return bf1(x) | (bf1(y) << 16); }
__device__ inline float2 unp_bf2(unsigned u){
  union {unsigned i; float f;} a, b;
  a.i = u << 16; b.i = u & 0xffff0000u;
  return make_float2(a.f, b.f);
}

__device__ inline void gld_lds16(const void* g, void* l){
  __builtin_amdgcn_global_load_lds((const __attribute__((address_space(1))) void*)g,
                                   (__attribute__((address_space(3))) void*)l, 16, 0, 0);
}

// ---------------- utility ----------------
__global__ void k_zero_f32(float* __restrict__ p, int n){
  int i = blockIdx.x * 256 + threadIdx.x; if (i < n) p[i] = 0.f;
}
__global__ void k_zero_i32(int* __restrict__ p, int n){
  int i = blockIdx.x * 256 + threadIdx.x; if (i < n) p[i] = 0;
}
// x (16,12000,3) -> xT (12000,16,3)
__global__ void k_transpose_in(const float* __restrict__ x, float* __restrict__ xT){
  int gid = blockIdx.x * 256 + threadIdx.x;
  if (gid >= 16 * 12000 * 3) return;
  int b = gid / 36000; int r = gid % 36000; int n = r / 3; int c = r % 3;
  xT[n * 48 + b * 3 + c] = x[gid];
}

// ---------------- CSR build (consolidated: 4 dispatches total) ----------------
__global__ void k_count_all(const int* __restrict__ ei0, const int* __restrict__ ei1,
                            const int* __restrict__ ei2, const int* __restrict__ ei3,
                            int* __restrict__ cnt0, int* __restrict__ cnt1,
                            int* __restrict__ cnt2, int* __restrict__ cnt3){
  int g = blockIdx.x * 256 + threadIdx.x;
  const int* ei; int* cnt; int e, E;
  if (g < 72000){ ei = ei0; cnt = cnt0; e = g; E = 72000; }
  else if (g < 90000){ ei = ei1; cnt = cnt1; e = g - 72000; E = 18000; }
  else if (g < 94500){ ei = ei2; cnt = cnt2; e = g - 90000; E = 4500; }
  else if (g < 95628){ ei = ei3; cnt = cnt3; e = g - 94500; E = 1128; }
  else return;
  atomicAdd(&cnt[ei[E + e]], 1);
}
// blockIdx.x = level; wave-shuffle block scan, 2 barriers total per level
__global__ void k_scan_all(int* c0, int* c1, int* c2, int* c3,
                           int* r0, int* r1, int* r2, int* r3){
  int lvl = blockIdx.x;
  int* cnt    = lvl == 0 ? c0 : lvl == 1 ? c1 : lvl == 2 ? c2 : c3;
  int* rowptr = lvl == 0 ? r0 : lvl == 1 ? r1 : lvl == 2 ? r2 : r3;
  int n       = lvl == 0 ? 12000 : lvl == 1 ? 3000 : lvl == 2 ? 750 : 188;
  int t = threadIdx.x;
  int L = (n + 255) / 256;
  int beg = t * L, end = min(n, beg + L);
  int s = 0;
  for (int i = beg; i < end; ++i) s += cnt[i];
  int lane = t & 63, wv = t >> 6;
  int incl = s;
  #pragma unroll
  for (int d = 1; d < 64; d <<= 1){
    int v = __shfl_up(incl, d, 64);
    if (lane >= d) incl += v;
  }
  __shared__ int wsum[4];
  if (lane == 63) wsum[wv] = incl;
  __syncthreads();
  int wbase = 0;
  for (int i = 0; i < wv; ++i) wbase += wsum[i];
  int run = wbase + incl - s;   // exclusive prefix for this thread's segment
  for (int i = beg; i < end; ++i){
    int v = cnt[i];
    cnt[i] = run;               // cursor = exclusive prefix
    run += v;
    rowptr[i + 1] = run;
  }
  if (t == 0) rowptr[0] = 0;
}
__global__ void k_fill_all(const int* __restrict__ ei0, const int* __restrict__ ei1,
                           const int* __restrict__ ei2, const int* __restrict__ ei3,
                           int* __restrict__ c0, int* __restrict__ c1,
                           int* __restrict__ c2, int* __restrict__ c3,
                           int* __restrict__ p0, int* __restrict__ p1,
                           int* __restrict__ p2, int* __restrict__ p3){
  int g = blockIdx.x * 256 + threadIdx.x;
  const int* ei; int* cur; int* perm; int e, E;
  if (g < 72000){ ei = ei0; cur = c0; perm = p0; e = g; E = 72000; }
  else if (g < 90000){ ei = ei1; cur = c1; perm = p1; e = g - 72000; E = 18000; }
  else if (g < 94500){ ei = ei2; cur = c2; perm = p2; e = g - 90000; E = 4500; }
  else if (g < 95628){ ei = ei3; cur = c3; perm = p3; e = g - 94500; E = 1128; }
  else return;
  int p = atomicAdd(&cur[ei[E + e]], 1);
  perm[p] = e;
}

// ---------------- fp32 -> bf16 converters for GEMM operands ----------------
__global__ void k_cvt_pad(const float* __restrict__ in, unsigned short* __restrict__ out,
                          int M, int K, int Kp, int total8){
  int gid = blockIdx.x * 256 + threadIdx.x;
  if (gid >= total8) return;
  int j = gid * 8;
  int row = j / Kp, col = j % Kp;
  float v[8];
  if (row < M && col + 8 <= K && (K & 3) == 0){
    const float* p = in + (size_t)row * K + col;
    float4 x0 = *(const float4*)p;
    float4 x1 = *(const float4*)(p + 4);
    v[0]=x0.x; v[1]=x0.y; v[2]=x0.z; v[3]=x0.w;
    v[4]=x1.x; v[5]=x1.y; v[6]=x1.z; v[7]=x1.w;
  } else {
    #pragma unroll
    for (int c = 0; c < 8; ++c)
      v[c] = (row < M && col + c < K) ? in[(size_t)row * K + col + c] : 0.f;
  }
  uint4 o;
  o.x = pack_bf2(v[0], v[1]); o.y = pack_bf2(v[2], v[3]);
  o.z = pack_bf2(v[4], v[5]); o.w = pack_bf2(v[6], v[7]);
  *(uint4*)(out + (size_t)gid * 8) = o;
}
__global__ void k_cvt_T(const float* __restrict__ in, unsigned short* __restrict__ out,
                        int K, int N, int Kp){
  __shared__ float ts[32][33];
  int t = threadIdx.x;
  int k0 = blockIdx.x * 32, n0 = blockIdx.y * 32;
  #pragma unroll
  for (int rep = 0; rep < 4; ++rep){
    int i = t + rep * 256;
    int kr = i >> 5, nc = i & 31;
    ts[kr][nc] = (k0 + kr < K) ? in[(size_t)(k0 + kr) * N + n0 + nc] : 0.f;
  }
  __syncthreads();
  #pragma unroll
  for (int rep = 0; rep < 4; ++rep){
    int i = t + rep * 256;
    int nr = i >> 5, kc = i & 31;
    out[(size_t)(n0 + nr) * Kp + k0 + kc] = (unsigned short)bf1(ts[kc][nr]);
  }
}

// ---------------- bf16 MFMA GEMM, double-buffered LDS ----------------
// C(M,N) (+)= A(Mp,Kp) @ Bt(N,Kp)^T. BK=32, 2 stages (8KB each per operand).
// Loads for chunk i+1 are issued AFTER barrier i, so barrier i drains only
// chunk i; chunk i+1 flies during compute i (latency hidden by compute +
// ~5 blocks/CU of cross-block overlap at 32KB LDS).
__global__ __launch_bounds__(256) void k_mgemm(const unsigned short* __restrict__ A,
                                               const unsigned short* __restrict__ Bt,
                                               float* __restrict__ C,
                                               int M, int N, int Kp, int Kc, int splitK){
  __shared__ __align__(16) short As[2 * 4096];   // 2 stages x 128 rows x 32 k
  __shared__ __align__(16) short Bs[2 * 4096];
  int t = threadIdx.x, lane = t & 63, w = t >> 6;
  int n0 = blockIdx.x << 7, m0 = blockIdx.y << 7;
  int k0 = blockIdx.z * Kc;
  int kend = min(Kp, k0 + Kc);
  int iters = (kend - k0 + 31) >> 5;             // Kp,Kc multiples of 32 here
  int s0 = w * 128 + lane, s1 = s0 + 64;
  const unsigned short* gA0 = A + (size_t)(m0 + (s0 & 127)) * Kp + (s0 >> 7) * 8 + k0;
  const unsigned short* gA1 = A + (size_t)(m0 + (s1 & 127)) * Kp + (s1 >> 7) * 8 + k0;
  const unsigned short* gB0 = Bt + (size_t)(n0 + (s0 & 127)) * Kp + (s0 >> 7) * 8 + k0;
  const unsigned short* gB1 = Bt + (size_t)(n0 + (s1 & 127)) * Kp + (s1 >> 7) * 8 + k0;
  short* lA0 = As + (size_t)(w * 128) * 8;       // wave-uniform bases (lane x 16B HW)
  short* lA1 = As + (size_t)(w * 128 + 64) * 8;
  short* lB0 = Bs + (size_t)(w * 128) * 8;
  short* lB1 = Bs + (size_t)(w * 128 + 64) * 8;
  f32x4 acc[4][4];
  #pragma unroll
  for (int mt = 0; mt < 4; ++mt)
    #pragma unroll
    for (int nt = 0; nt < 4; ++nt){ acc[mt][nt][0]=0.f; acc[mt][nt][1]=0.f; acc[mt][nt][2]=0.f; acc[mt][nt][3]=0.f; }
  int q = lane >> 4, r = lane & 15;
  int mrow = (w >> 1) * 64, nrow = (w & 1) * 64;
  const short* pa = As + (size_t)(q * 128 + mrow + r) * 8;
  const short* pb = Bs + (size_t)(q * 128 + nrow + r) * 8;
  // prologue: stage 0
  gld_lds16(gA0, lA0); gld_lds16(gA1, lA1);
  gld_lds16(gB0, lB0); gld_lds16(gB1, lB1);
  for (int i = 0; i < iters; ++i){
    int st = i & 1;
    __syncthreads();                             // drains chunk i loads only
    if (i + 1 < iters){                          // issue chunk i+1 into other stage
      int nst = st ^ 1;
      int off = (i + 1) * 32;
      gld_lds16(gA0 + off, lA0 + nst * 4096);
      gld_lds16(gA1 + off, lA1 + nst * 4096);
      gld_lds16(gB0 + off, lB0 + nst * 4096);
      gld_lds16(gB1 + off, lB1 + nst * 4096);
    }
    const short* pas = pa + st * 4096;
    const short* pbs = pb + st * 4096;
    bf16x8 af[4], bg[4];
    #pragma unroll
    for (int mt = 0; mt < 4; ++mt) af[mt] = *(const bf16x8*)(pas + mt * 128);
    #pragma unroll
    for (int nt = 0; nt < 4; ++nt) bg[nt] = *(const bf16x8*)(pbs + nt * 128);
    #pragma unroll
    for (int mt = 0; mt < 4; ++mt)
      #pragma unroll
      for (int nt = 0; nt < 4; ++nt)
        acc[mt][nt] = __builtin_amdgcn_mfma_f32_16x16x32_bf16(af[mt], bg[nt], acc[mt][nt], 0, 0, 0);
  }
  int mb = m0 + mrow + q * 4;
  int nb = n0 + nrow + r;
  #pragma unroll
  for (int mt = 0; mt < 4; ++mt){
    #pragma unroll
    for (int reg = 0; reg < 4; ++reg){
      int m = mb + mt * 16 + reg;
      if (m < M){
        float* cp = C + (size_t)m * N + nb;
        if (splitK > 1){
          #pragma unroll
          for (int nt = 0; nt < 4; ++nt) atomicAdd(cp + nt * 16, acc[mt][nt][reg]);
        } else {
          #pragma unroll
          for (int nt = 0; nt < 4; ++nt) cp[nt * 16] = acc[mt][nt][reg];
        }
      }
    }
  }
}

// ---------------- k materialization ----------------
__global__ __launch_bounds__(256) void k_kmat_big(const float* __restrict__ ec, const float* __restrict__ W,
                                                  unsigned short* __restrict__ kbuf, int E, int CiCo4){
  __shared__ float ecs[128];
  int t = threadIdx.x;
  int e0 = blockIdx.y * 8;
  if (t < 128){ int el = t >> 4, w = t & 15; int e = e0 + el; ecs[t] = (e < E) ? ec[e * 16 + w] : 0.f; }
  __syncthreads();
  int j4 = blockIdx.x * 256 + t;
  const float4* W4 = (const float4*)W;
  float4 w16[16];
  #pragma unroll
  for (int w = 0; w < 16; ++w) w16[w] = W4[(size_t)w * CiCo4 + j4];
  uint2* k2 = (uint2*)kbuf;
  #pragma unroll 1
  for (int el = 0; el < 8; ++el){
    int e = e0 + el; if (e >= E) break;
    float4 a = {0.f, 0.f, 0.f, 0.f};
    #pragma unroll
    for (int w = 0; w < 16; ++w){
      float s = ecs[el * 16 + w];
      a.x += s * w16[w].x; a.y += s * w16[w].y; a.z += s * w16[w].z; a.w += s * w16[w].w;
    }
    k2[(size_t)e * CiCo4 + j4] = make_uint2(pack_bf2(a.x, a.y), pack_bf2(a.z, a.w));
  }
}
__global__ __launch_bounds__(256) void k_kmat_small(const float* __restrict__ ec, const float* __restrict__ W,
                                                    unsigned short* __restrict__ kbuf, int E){
  __shared__ float4 Ws[16 * 24];
  __shared__ float ecs[32 * 16];
  int t = threadIdx.x;
  for (int i = t; i < 384; i += 256) Ws[i] = ((const float4*)W)[i];
  int e0 = blockIdx.x * 32;
  for (int i = t; i < 512; i += 256){ int el = i >> 4, w = i & 15; int e = e0 + el; ecs[i] = (e < E) ? ec[e * 16 + w] : 0.f; }
  __syncthreads();
  int el = t >> 3, jj = t & 7;
  int e = e0 + el;
  if (e >= E) return;
  uint2* k2 = (uint2*)kbuf;
  #pragma unroll 1
  for (int rep = 0; rep < 3; ++rep){
    int j4 = jj + rep * 8;
    float4 a = {0.f, 0.f, 0.f, 0.f};
    #pragma unroll
    for (int w = 0; w < 16; ++w){
      float s = ecs[el * 16 + w];
      float4 wv = Ws[w * 24 + j4];
      a.x += s * wv.x; a.y += s * wv.y; a.z += s * wv.z; a.w += s * wv.w;
    }
    k2[(size_t)e * 24 + j4] = make_uint2(pack_bf2(a.x, a.y), pack_bf2(a.z, a.w));
  }
}

// ---------------- level-0 convs ----------------
__global__ __launch_bounds__(256) void k_conv_l0_enc(const float* __restrict__ xT, const unsigned short* __restrict__ kbuf,
                                                     const int* __restrict__ ei, const int* __restrict__ rowptr,
                                                     const int* __restrict__ perm, const float* __restrict__ bias,
                                                     float* __restrict__ out){
  int gid = blockIdx.x * 256 + threadIdx.x;
  int n = gid >> 4, b = gid & 15;
  if (n >= 12000) return;
  float acc[32];
  #pragma unroll
  for (int o = 0; o < 32; ++o) acc[o] = 0.f;
  int r1 = rowptr[n + 1];
  for (int r = rowptr[n]; r < r1; ++r){
    int e = perm[r];
    int src = ei[e];
    const float* xp = xT + src * 48 + b * 3;
    float xv[3] = {xp[0], xp[1], xp[2]};
    const uint4* kq = (const uint4*)(kbuf + (size_t)e * 96);
    #pragma unroll
    for (int i = 0; i < 3; ++i){
      #pragma unroll
      for (int o8 = 0; o8 < 4; ++o8){
        uint4 u = kq[i * 4 + o8];
        float2 f0 = unp_bf2(u.x), f1 = unp_bf2(u.y), f2 = unp_bf2(u.z), f3 = unp_bf2(u.w);
        int ob = o8 * 8;
        acc[ob + 0] += xv[i] * f0.x; acc[ob + 1] += xv[i] * f0.y;
        acc[ob + 2] += xv[i] * f1.x; acc[ob + 3] += xv[i] * f1.y;
        acc[ob + 4] += xv[i] * f2.x; acc[ob + 5] += xv[i] * f2.y;
        acc[ob + 6] += xv[i] * f3.x; acc[ob + 7] += xv[i] * f3.y;
      }
    }
  }
  float4* op = (float4*)(out + (size_t)n * 512 + b * 32);
  #pragma unroll
  for (int o4 = 0; o4 < 8; ++o4){
    float4 v;
    v.x = fmaxf(acc[o4 * 4 + 0] + bias[o4 * 4 + 0], 0.f);
    v.y = fmaxf(acc[o4 * 4 + 1] + bias[o4 * 4 + 1], 0.f);
    v.z = fmaxf(acc[o4 * 4 + 2] + bias[o4 * 4 + 2], 0.f);
    v.w = fmaxf(acc[o4 * 4 + 3] + bias[o4 * 4 + 3], 0.f);
    op[o4] = v;
  }
}
__global__ __launch_bounds__(256) void k_conv_l0_dec(const float* __restrict__ xin, const unsigned short* __restrict__ kbuf,
                                                     const int* __restrict__ ei, const int* __restrict__ rowptr,
                                                     const int* __restrict__ perm, const float* __restrict__ bias,
                                                     float* __restrict__ out){
  int gid = blockIdx.x * 256 + threadIdx.x;
  int n = gid >> 4, b = gid & 15;
  if (n >= 12000) return;
  float acc0 = 0.f, acc1 = 0.f, acc2 = 0.f;
  int r1 = rowptr[n + 1];
  for (int r = rowptr[n]; r < r1; ++r){
    int e = perm[r];
    int src = ei[e];
    const float4* xr = (const float4*)(xin + (size_t)src * 512 + b * 32);
    const unsigned* kw = (const unsigned*)(kbuf + (size_t)e * 96);
    #pragma unroll
    for (int c = 0; c < 8; ++c){
      float4 xv = xr[c];
      float2 p0 = unp_bf2(kw[6 * c + 0]);
      float2 p1 = unp_bf2(kw[6 * c + 1]);
      float2 p2 = unp_bf2(kw[6 * c + 2]);
      float2 p3 = unp_bf2(kw[6 * c + 3]);
      float2 p4 = unp_bf2(kw[6 * c + 4]);
      float2 p5 = unp_bf2(kw[6 * c + 5]);
      acc0 += xv.x * p0.x; acc1 += xv.x * p0.y; acc2 += xv.x * p1.x;
      acc0 += xv.y * p1.y; acc1 += xv.y * p2.x; acc2 += xv.y * p2.y;
      acc0 += xv.z * p3.x; acc1 += xv.z * p3.y; acc2 += xv.z * p4.x;
      acc0 += xv.w * p4.y; acc1 += xv.w * p5.x; acc2 += xv.w * p5.y;
    }
  }
  float* op = out + (size_t)b * 36000 + n * 3;
  op[0] = acc0 + bias[0];
  op[1] = acc1 + bias[1];
  op[2] = acc2 + bias[2];
}

// ---------------- mid-level conv, CO-split S via blockIdx.y ----------------
template<int CI, int CO, int S, bool RELU>
__global__ __launch_bounds__(256) void k_conv_mid(const float* __restrict__ xin, const unsigned short* __restrict__ kbuf,
                                                  const int* __restrict__ ei, const int* __restrict__ rowptr,
                                                  const int* __restrict__ perm, const float* __restrict__ bias,
                                                  float* __restrict__ out){
  constexpr int COC = CO / S;
  constexpr int V   = COC / 16;
  constexpr int IT  = (CI > 64) ? 64 : CI;
  constexpr int NIH = CI / IT;
  constexpr int COP = COC + 4;
  constexpr int XP  = IT + 4;
  __shared__ float ks[IT * COP];
  __shared__ float xs[16 * XP];
  int n = blockIdx.x, cy = blockIdx.y;
  int ob0 = cy * COC;
  int t = threadIdx.x;
  int og = t >> 4, b = t & 15;
  float acc[V];
  #pragma unroll
  for (int j = 0; j < V; ++j) acc[j] = 0.f;
  int r0 = rowptr[n], r1 = rowptr[n + 1];
  for (int r = r0; r < r1; ++r){
    int e = perm[r];
    int src = ei[e];
    const float4* xbase = (const float4*)(xin + (size_t)src * (16 * CI));
    for (int ih = 0; ih < NIH; ++ih){
      __syncthreads();
      const uint4* kb = (const uint4*)(kbuf + (size_t)e * (CI * CO) + ih * (IT * CO));
      constexpr int KS8 = IT * COC / 8;
      for (int i8 = t; i8 < KS8; i8 += 256){
        int i = (i8 * 8) / COC, o = (i8 * 8) % COC;
        uint4 u = kb[(i * CO + ob0 + o) >> 3];
        float* d = &ks[i * COP + o];
        float2 f0 = unp_bf2(u.x), f1 = unp_bf2(u.y), f2 = unp_bf2(u.z), f3 = unp_bf2(u.w);
        *(float4*)&d[0] = make_float4(f0.x, f0.y, f1.x, f1.y);
        *(float4*)&d[4] = make_float4(f2.x, f2.y, f3.x, f3.y);
      }
      constexpr int XS4 = 16 * IT / 4;
      for (int i4 = t; i4 < XS4; i4 += 256){
        int bb = i4 / (IT / 4), iq = i4 % (IT / 4);
        float4 v = xbase[bb * (CI / 4) + ih * (IT / 4) + iq];
        *(float4*)&xs[bb * XP + iq * 4] = v;
      }
      __syncthreads();
      #pragma unroll 4
      for (int i = 0; i < IT; ++i){
        float xv = xs[b * XP + i];
        if constexpr (V == 8){
          const float4* kp = (const float4*)&ks[i * COP + og * 8];
          float4 p0 = kp[0], p1 = kp[1];
          acc[0] += xv * p0.x; acc[1] += xv * p0.y; acc[2] += xv * p0.z; acc[3] += xv * p0.w;
          acc[4] += xv * p1.x; acc[5] += xv * p1.y; acc[6] += xv * p1.z; acc[7] += xv * p1.w;
        } else if constexpr (V == 4){
          float4 p0 = *(const float4*)&ks[i * COP + og * 4];
          acc[0] += xv * p0.x; acc[1] += xv * p0.y; acc[2] += xv * p0.z; acc[3] += xv * p0.w;
        } else {
          float2 p0 = *(const float2*)&ks[i * COP + og * 2];
          acc[0] += xv * p0.x; acc[1] += xv * p0.y;
        }
      }
    }
  }
  float* op = out + (size_t)n * (16 * CO) + b * CO + ob0 + og * V;
  #pragma unroll
  for (int j = 0; j < V; ++j){
    float v = acc[j] + bias[ob0 + og * V + j];
    if (RELU) v = fmaxf(v, 0.f);
    op[j] = v;
  }
}

// ---------------- bottleneck FCs ----------------
__global__ void k_encfc(const float* __restrict__ x, const float* __restrict__ encW,
                        const float* __restrict__ encb, float* __restrict__ z){
  __shared__ float red[128];
  int bq = blockIdx.x; int b = bq >> 3, q = bq & 7;
  int t = threadIdx.x;
  float s = 0.f;
  for (int j = t; j < 6016; j += 128){
    int n = j >> 7, c = j & 127;
    s += x[n * 2048 + b * 128 + c] * encW[q * 6016 + j];
  }
  red[t] = s; __syncthreads();
  for (int o = 64; o > 0; o >>= 1){ if (t < o) red[t] += red[t + o]; __syncthreads(); }
  if (t == 0) z[b * 8 + q] = red[0] + encb[q];
}
__global__ void k_decfc(const float* __restrict__ z, const float* __restrict__ decW,
                        const float* __restrict__ decb, float* __restrict__ y){
  int gid = blockIdx.x * 256 + threadIdx.x;
  if (gid >= 6016 * 16) return;
  int c = gid & 127, bn = gid >> 7; int b = bn & 15, n = bn >> 4;
  int j = n * 128 + c;
  float s = decb[j];
  #pragma unroll
  for (int q = 0; q < 8; ++q) s += z[b * 8 + q] * decW[j * 8 + q];
  y[gid] = s;
}

// ---------------------------------------------------------------------------
extern "C" void kernel_launch(void* const* d_in, const int* in_sizes, int n_in,
                              void* d_out, int out_size, void* d_ws, size_t ws_size,
                              hipStream_t stream){
  const float* x   = (const float*)d_in[0];
  const int*   ei0 = (const int*)d_in[1];  const float* ec0 = (const float*)d_in[2];
  const int*   ei1 = (const int*)d_in[3];  const float* ec1 = (const float*)d_in[4];
  const int*   ei2 = (const int*)d_in[5];  const float* ec2 = (const float*)d_in[6];
  const int*   ei3 = (const int*)d_in[7];  const float* ec3 = (const float*)d_in[8];
  const float* Wc0 = (const float*)d_in[11], *bc0 = (const float*)d_in[12];
  const float* Wd0 = (const float*)d_in[13], *bd0 = (const float*)d_in[14];
  const float* dm0 = (const float*)d_in[15], *um0 = (const float*)d_in[16];
  const float* Wc1 = (const float*)d_in[17], *bc1 = (const float*)d_in[18];
  const float* Wd1 = (const float*)d_in[19], *bd1 = (const float*)d_in[20];
  const float* dm1 = (const float*)d_in[21], *um1 = (const float*)d_in[22];
  const float* Wc2 = (const float*)d_in[23], *bc2 = (const float*)d_in[24];
  const float* Wd2 = (const float*)d_in[25], *bd2 = (const float*)d_in[26];
  const float* dm2 = (const float*)d_in[27], *um2 = (const float*)d_in[28];
  const float* Wc3 = (const float*)d_in[29], *bc3 = (const float*)d_in[30];
  const float* Wd3 = (const float*)d_in[31], *bd3 = (const float*)d_in[32];
  const float* dm3 = (const float*)d_in[33], *um3 = (const float*)d_in[34];
  const float* encW = (const float*)d_in[35], *encb = (const float*)d_in[36];
  const float* decW = (const float*)d_in[37], *decb = (const float*)d_in[38];

  // workspace layout (~138 MiB)
  char* wsb = (char*)d_ws;
  unsigned short* kbuf = (unsigned short*)wsb;                    // shared with Abf
  unsigned short* Abf  = kbuf;
  float* bufA = (float*)(wsb + 73728000);
  float* bufB = (float*)(wsb + 98304000);
  unsigned short* Bt = (unsigned short*)(wsb + 122880000);
  float* xT   = (float*)(wsb + 135168000);
  float* zb   = (float*)(wsb + 137472000);
  int* ip = (int*)(wsb + 137472512);
  int* cnt0 = ip; ip += 12000;
  int* cnt1 = ip; ip += 3000;
  int* cnt2 = ip; ip += 750;
  int* cnt3 = ip; ip += 188;
  int* row0 = ip; ip += 12001;
  int* row1 = ip; ip += 3001;
  int* row2 = ip; ip += 751;
  int* row3 = ip; ip += 189;
  int* perm0 = ip; ip += 72000;
  int* perm1 = ip; ip += 18000;
  int* perm2 = ip; ip += 4500;
  int* perm3 = ip; ip += 1128;

  dim3 blk(256);
  // input transpose + CSR build (4 dispatches)
  k_transpose_in<<<2250, blk, 0, stream>>>(x, xT);
  k_zero_i32<<<63, blk, 0, stream>>>(cnt0, 15938);
  k_count_all<<<374, blk, 0, stream>>>(ei0, ei1, ei2, ei3, cnt0, cnt1, cnt2, cnt3);
  k_scan_all<<<4, blk, 0, stream>>>(cnt0, cnt1, cnt2, cnt3, row0, row1, row2, row3);
  k_fill_all<<<374, blk, 0, stream>>>(ei0, ei1, ei2, ei3, cnt0, cnt1, cnt2, cnt3,
                                      perm0, perm1, perm2, perm3);

  // ---- encoder ----
  k_kmat_small<<<2250, blk, 0, stream>>>(ec0, Wc0, kbuf, 72000);
  k_conv_l0_enc<<<750, blk, 0, stream>>>(xT, kbuf, ei0, row0, perm0, bc0, bufA);          // a0 (12000,512)
  k_cvt_T<<<dim3(375, 16), blk, 0, stream>>>(bufA, Bt, 12000, 512, 12000);
  k_cvt_pad<<<18000, blk, 0, stream>>>(dm0, Abf, 3000, 12000, 12000, 4608000);
  k_zero_f32<<<6000, blk, 0, stream>>>(bufB, 1536000);
  k_mgemm<<<dim3(4, 24, 8), blk, 0, stream>>>(Abf, Bt, bufB, 3000, 512, 12000, 1504, 8);  // p0 (3000,512)
  k_kmat_big<<<dim3(2, 2250), blk, 0, stream>>>(ec1, Wc1, kbuf, 18000, 512);
  k_conv_mid<32, 64, 1, true><<<dim3(3000, 1), blk, 0, stream>>>(bufB, kbuf, ei1, row1, perm1, bc1, bufA); // a1
  k_cvt_T<<<dim3(94, 32), blk, 0, stream>>>(bufA, Bt, 3000, 1024, 3008);
  k_cvt_pad<<<1128, blk, 0, stream>>>(dm1, Abf, 750, 3000, 3008, 288768);
  k_zero_f32<<<3000, blk, 0, stream>>>(bufB, 768000);
  k_mgemm<<<dim3(8, 6, 8), blk, 0, stream>>>(Abf, Bt, bufB, 750, 1024, 3008, 384, 8);     // p1 (750,1024)
  k_kmat_big<<<dim3(8, 563), blk, 0, stream>>>(ec2, Wc2, kbuf, 4500, 2048);
  k_conv_mid<64, 128, 4, true><<<dim3(750, 4), blk, 0, stream>>>(bufB, kbuf, ei2, row2, perm2, bc2, bufA); // a2
  k_cvt_T<<<dim3(24, 64), blk, 0, stream>>>(bufA, Bt, 750, 2048, 768);
  k_cvt_pad<<<96, blk, 0, stream>>>(dm2, Abf, 188, 750, 768, 24576);
  k_zero_f32<<<1504, blk, 0, stream>>>(bufB, 385024);
  k_mgemm<<<dim3(16, 2, 8), blk, 0, stream>>>(Abf, Bt, bufB, 188, 2048, 768, 96, 8);      // p2 (188,2048)
  k_kmat_big<<<dim3(16, 141), blk, 0, stream>>>(ec3, Wc3, kbuf, 1128, 4096);
  k_conv_mid<128, 128, 4, true><<<dim3(188, 4), blk, 0, stream>>>(bufB, kbuf, ei3, row3, perm3, bc3, bufA); // a3
  k_cvt_T<<<dim3(6, 64), blk, 0, stream>>>(bufA, Bt, 188, 2048, 192);
  k_cvt_pad<<<12, blk, 0, stream>>>(dm3, Abf, 47, 188, 192, 3072);
  k_zero_f32<<<376, blk, 0, stream>>>(bufB, 96256);
  k_mgemm<<<dim3(16, 1, 6), blk, 0, stream>>>(Abf, Bt, bufB, 47, 2048, 192, 32, 6);       // p3 (47,2048)

  // ---- bottleneck ----
  k_encfc<<<128, dim3(128), 0, stream>>>(bufB, encW, encb, zb);
  k_decfc<<<376, blk, 0, stream>>>(zb, decW, decb, bufA);                                 // y' (47,2048)

  // ---- decoder ----
  k_cvt_T<<<dim3(2, 64), blk, 0, stream>>>(bufA, Bt, 47, 2048, 64);
  k_cvt_pad<<<8, blk, 0, stream>>>(um3, Abf, 188, 47, 64, 2048);
  k_zero_f32<<<1504, blk, 0, stream>>>(bufB, 385024);
  k_mgemm<<<dim3(16, 2, 2), blk, 0, stream>>>(Abf, Bt, bufB, 188, 2048, 64, 32, 2);       // u3 (188,2048)
  k_kmat_big<<<dim3(16, 141), blk, 0, stream>>>(ec3, Wd0, kbuf, 1128, 4096);
  k_conv_mid<128, 128, 4, true><<<dim3(188, 4), blk, 0, stream>>>(bufB, kbuf, ei3, row3, perm3, bd0, bufA); // d0
  k_cvt_T<<<dim3(6, 64), blk, 0, stream>>>(bufA, Bt, 188, 2048, 192);
  k_cvt_pad<<<72, blk, 0, stream>>>(um2, Abf, 750, 188, 192, 18432);
  k_zero_f32<<<6000, blk, 0, stream>>>(bufB, 1536000);
  k_mgemm<<<dim3(16, 6, 2), blk, 0, stream>>>(Abf, Bt, bufB, 750, 2048, 192, 96, 2);      // u2 (750,2048)
  k_kmat_big<<<dim3(8, 563), blk, 0, stream>>>(ec2, Wd1, kbuf, 4500, 2048);
  k_conv_mid<128, 64, 2, true><<<dim3(750, 2), blk, 0, stream>>>(bufB, kbuf, ei2, row2, perm2, bd1, bufA); // d1
  k_cvt_T<<<dim3(24, 32), blk, 0, stream>>>(bufA, Bt, 750, 1024, 768);
  k_cvt_pad<<<1152, blk, 0, stream>>>(um1, Abf, 3000, 750, 768, 294912);
  k_zero_f32<<<12000, blk, 0, stream>>>(bufB, 3072000);
  k_mgemm<<<dim3(8, 24, 4), blk, 0, stream>>>(Abf, Bt, bufB, 3000, 1024, 768, 192, 4);    // u1 (3000,1024)
  k_kmat_big<<<dim3(2, 2250), blk, 0, stream>>>(ec1, Wd2, kbuf, 18000, 512);
  k_conv_mid<64, 32, 1, true><<<dim3(3000, 1), blk, 0, stream>>>(bufB, kbuf, ei1, row1, perm1, bd2, bufA); // d2
  k_cvt_T<<<dim3(94, 16), blk, 0, stream>>>(bufA, Bt, 3000, 512, 3008);
  k_cvt_pad<<<17672, blk, 0, stream>>>(um0, Abf, 12000, 3000, 3008, 4524032);
  k_zero_f32<<<24000, blk, 0, stream>>>(bufB, 6144000);
  k_mgemm<<<dim3(4, 94, 2), blk, 0, stream>>>(Abf, Bt, bufB, 12000, 512, 3008, 1504, 2);  // u0 (12000,512)
  k_kmat_small<<<2250, blk, 0, stream>>>(ec0, Wd3, kbuf, 72000);
  k_conv_l0_dec<<<750, blk, 0, stream>>>(bufB, kbuf, ei0, row0, perm0, bd3, (float*)d_out);
}